// Round 6
// baseline (16619.339 us; speedup 1.0000x reference)
//
#include <hip/hip_runtime.h>
#include <cstdint>
#include <cstddef>

#define BATCH  128
#define SEQT   512
#define EMB_D  300
#define VOCABN 5000
#define KP0    320          // EMB_D padded to mult of 32
#define NU0    256
#define NU1    512
#define NU2    256
#define NDENSE 64

typedef unsigned short ushortT;
typedef __attribute__((ext_vector_type(8))) short bf16x8;
typedef __attribute__((ext_vector_type(8))) unsigned short u16x8;
typedef __attribute__((ext_vector_type(4))) float f32x4;

static __device__ __forceinline__ unsigned short f2bf(float x) {
    union { float f; unsigned u; } v; v.f = x;
    const unsigned r = v.u + 0x7FFFu + ((v.u >> 16) & 1u);
    return (unsigned short)(r >> 16);
}
static __device__ __forceinline__ float bf2f(unsigned short b) {
    union { unsigned u; float f; } v; v.u = ((unsigned)b) << 16;
    return v.f;
}
static __device__ __forceinline__ float sigmoidf_(float x) {
    return 1.f / (1.f + __expf(-x));
}

// ---------------------------------------------------------------------------
// One-time converts: W [K][NG] f32 -> WbfT [NG][KP] bf16 (transposed, padded);
// emb [VOCAB][300] f32 -> embbf [VOCAB][KP0] bf16 (padded).
// ---------------------------------------------------------------------------
__global__ __launch_bounds__(256) void convert_WT(
    const float* __restrict__ W, ushortT* __restrict__ WbfT,
    int K, int NG, int KP, int total)
{
    for (int idx = blockIdx.x * 256 + threadIdx.x; idx < total; idx += gridDim.x * 256) {
        const int m = idx / KP, k = idx - m * KP;
        WbfT[idx] = (k < K) ? f2bf(W[(size_t)k * NG + m]) : (ushortT)0;
    }
}
__global__ __launch_bounds__(256) void convert_emb(
    const float* __restrict__ emb, ushortT* __restrict__ embbf)
{
    const int total = VOCABN * KP0;
    for (int idx = blockIdx.x * 256 + threadIdx.x; idx < total; idx += gridDim.x * 256) {
        const int v = idx / KP0, k = idx - v * KP0;
        embbf[idx] = (k < EMB_D) ? f2bf(emb[(size_t)v * EMB_D + k]) : (ushortT)0;
    }
}

// ---------------------------------------------------------------------------
// MFMA GEMM: xgT[t][g][m][b16] = sum_k WbfT[m][k] * x_t[b][k] + bias[m]
// with b = g*16 + b16 (group-major output so each recurrence group reads a
// contiguous per-step slab). A = WbfT rows (M), B = x rows (N=batch).
// 16x16x32 bf16 MFMA, 128Mx128N tile, BK=32, 4 waves, XOR-swizzled LDS.
// MODE 0: x gathered from embbf via tokens; MODE 1: x = hseqX slab t.
// ---------------------------------------------------------------------------
template<int MODE>
__global__ __launch_bounds__(256) void gemm_mfma(
    const ushortT* __restrict__ Bsrc,
    const int*   __restrict__ tokens, int t0,
    const ushortT* __restrict__ WbfT,   // [NG][KP]
    const float* __restrict__ bias,     // [NG]
    float* __restrict__ xgT,            // [CH][8][NG][16]
    int NG, int KP)
{
    __shared__ ushortT Wl[128][32];
    __shared__ ushortT Xl[128][32];
    __shared__ int tokL[128];

    const int tid = threadIdx.x;
    const int t   = blockIdx.x;
    const int m0  = blockIdx.y * 128;
    const int wv  = tid >> 6;
    const int lane = tid & 63;
    const int lo  = lane & 15;
    const int hi  = lane >> 4;

    if (MODE == 0) {
        if (tid < 128) tokL[tid] = tokens[tid * SEQT + t0 + t];
        __syncthreads();
    }

    f32x4 acc[2][8];
    #pragma unroll
    for (int s = 0; s < 2; ++s)
        #pragma unroll
        for (int n = 0; n < 8; ++n)
            acc[s][n] = f32x4{0.f, 0.f, 0.f, 0.f};

    for (int k0 = 0; k0 < KP; k0 += 32) {
        #pragma unroll
        for (int it = 0; it < 2; ++it) {
            const int idx = tid + it * 256;          // 0..511
            const int row = idx >> 2, gq = idx & 3;
            const int gs  = gq ^ ((row >> 1) & 3);
            *(u16x8*)&Wl[row][gs * 8] =
                *(const u16x8*)(WbfT + (size_t)(m0 + row) * KP + k0 + gq * 8);
            const ushortT* xs;
            if (MODE == 0) xs = Bsrc + (size_t)tokL[row] * KP + k0 + gq * 8;
            else           xs = Bsrc + ((size_t)t * 128 + row) * KP + k0 + gq * 8;
            *(u16x8*)&Xl[row][gs * 8] = *(const u16x8*)xs;
        }
        __syncthreads();

        bf16x8 bfr[8];
        #pragma unroll
        for (int n = 0; n < 8; ++n) {
            const int row = n * 16 + lo;
            bfr[n] = *(const bf16x8*)&Xl[row][(hi ^ ((row >> 1) & 3)) * 8];
        }
        #pragma unroll
        for (int s = 0; s < 2; ++s) {
            const int row = wv * 32 + s * 16 + lo;
            const bf16x8 a = *(const bf16x8*)&Wl[row][(hi ^ ((row >> 1) & 3)) * 8];
            #pragma unroll
            for (int n = 0; n < 8; ++n)
                acc[s][n] = __builtin_amdgcn_mfma_f32_16x16x32_bf16(a, bfr[n], acc[s][n], 0, 0, 0);
        }
        __syncthreads();
    }

    // epilogue: C row = m, col = b = n*16 + lo  ->  xgT[t][n][m][lo]
    #pragma unroll
    for (int s = 0; s < 2; ++s) {
        #pragma unroll
        for (int j = 0; j < 4; ++j) {
            const int m = m0 + wv * 32 + s * 16 + hi * 4 + j;
            const float bi = bias[m];
            #pragma unroll
            for (int n = 0; n < 8; ++n)
                xgT[(((size_t)t * 8 + n) * NG + m) * 16 + lo] = acc[s][n][j] + bi;
        }
    }
}

// ---------------------------------------------------------------------------
// MFMA recurrence, XCD-local groups (g = blockIdx.x & 7), flag-based sync.
// Group owns 16 batch rows; WG owns 16 h-cols x 4 gates (one per wave);
// U cols persistent in bf16 B-fragments. Sync: per-WG epoch flags —
// wave2 release-stores flag[wgj]=t+1 after writing h; every wave spins on
// relaxed loads of the group's 32-word flag line until __all(>= t).
// No centralized RMW, no barrier syncthreads. xgT prefetched 1 step ahead.
// t=0 of the first chunk skips the MFMA (h0 == 0) -> no init round-trip.
// ---------------------------------------------------------------------------
template<int U_>
__global__ __launch_bounds__(256, 1) void lstm_mfma(
    const float* __restrict__ xgT,     // [CH][8][4U][16]
    const float* __restrict__ Umat,    // [U][4U] gates i,f,c,o
    ushortT* __restrict__ h0,          // carry / parity0 [128][U] bf16
    ushortT* __restrict__ h1,          // parity1 (ping-pong path) or unused
    float* __restrict__ cst,           // [128][U]
    ushortT* __restrict__ hseqX,       // [CH][128][U] bf16 or nullptr
    unsigned* __restrict__ flags,      // [8][32], zeroed before launch
    int CH, int init)
{
    constexpr int NG  = 4 * U_;
    constexpr int KT  = U_ / 32;
    constexpr int WPG = U_ / 16;

    __shared__ float ex[2][3][16][17];

    const int tid  = threadIdx.x;
    const int wv   = tid >> 6;
    const int lane = tid & 63;
    const int lo   = lane & 15;
    const int hi   = lane >> 4;
    const int g    = blockIdx.x & 7;          // XCD-local group
    const int wgj  = blockIdx.x >> 3;
    const int J    = wgj * 16;
    const int b0   = g * 16;
    const int gcol = wv * U_ + J + lo;
    const size_t S = (size_t)128 * U_;
    unsigned* gflag = flags + g * 32;
    const int fidx  = lane & (WPG - 1);

    // persistent B-fragments: U[:, gcol] in bf16
    bf16x8 bf[KT];
    #pragma unroll
    for (int kt = 0; kt < KT; ++kt) {
        const float* up = Umat + (size_t)(kt * 32 + hi * 8) * NG + gcol;
        bf16x8 v;
        #pragma unroll
        for (int i = 0; i < 8; ++i) v[i] = (short)f2bf(up[(size_t)i * NG]);
        bf[kt] = v;
    }

    float cr0 = 0.f, cr1 = 0.f, cr2 = 0.f, cr3 = 0.f;
    if (!init && wv == 2) {
        cr0 = cst[(size_t)(b0 + hi * 4 + 0) * U_ + J + lo];
        cr1 = cst[(size_t)(b0 + hi * 4 + 1) * U_ + J + lo];
        cr2 = cst[(size_t)(b0 + hi * 4 + 2) * U_ + J + lo];
        cr3 = cst[(size_t)(b0 + hi * 4 + 3) * U_ + J + lo];
    }

    const float* xpb = xgT + ((size_t)g * NG + gcol) * 16 + hi * 4;
    float4 xv = *(const float4*)xpb;          // t = 0

    for (int t = 0; t < CH; ++t) {
        float4 xvn = xv;
        if (t + 1 < CH)                        // prefetch next step's xg
            xvn = *(const float4*)(xpb + (size_t)(t + 1) * 8 * NG * 16);

        const ushortT* hrd;
        ushortT* hwr;
        if (hseqX) {
            hrd = t ? (hseqX + (size_t)(t - 1) * S) : h0;
            hwr = hseqX + (size_t)t * S;
        } else {
            hrd = (t & 1) ? h1 : h0;
            hwr = (t & 1) ? h0 : h1;
        }

        f32x4 acc  = {0.f, 0.f, 0.f, 0.f};
        f32x4 acc2 = {0.f, 0.f, 0.f, 0.f};
        if (!(init && t == 0)) {
            if (t > 0) {
                const unsigned tgt = (unsigned)t;
                int guard = 0;
                for (;;) {
                    const unsigned v = __hip_atomic_load(&gflag[fidx], __ATOMIC_RELAXED,
                                                         __HIP_MEMORY_SCOPE_AGENT);
                    if (__all((int)(v >= tgt))) break;
                    __builtin_amdgcn_s_sleep(1);
                    if (++guard > (1 << 22)) break;
                }
                (void)__hip_atomic_load(&gflag[fidx], __ATOMIC_ACQUIRE,
                                        __HIP_MEMORY_SCOPE_AGENT);
            }
            const ushortT* hb = hrd + (size_t)(b0 + lo) * U_;
            #pragma unroll
            for (int kt = 0; kt < KT; kt += 2) {
                const bf16x8 a0 = *(const bf16x8*)(hb + kt * 32 + hi * 8);
                acc  = __builtin_amdgcn_mfma_f32_16x16x32_bf16(a0, bf[kt], acc, 0, 0, 0);
                const bf16x8 a1 = *(const bf16x8*)(hb + (kt + 1) * 32 + hi * 8);
                acc2 = __builtin_amdgcn_mfma_f32_16x16x32_bf16(a1, bf[kt + 1], acc2, 0, 0, 0);
            }
            acc = acc + acc2;
        }

        const float p0 = acc[0] + xv.x;
        const float p1 = acc[1] + xv.y;
        const float p2 = acc[2] + xv.z;
        const float p3 = acc[3] + xv.w;
        xv = xvn;

        if (wv != 2) {
            const int slot = (wv == 3) ? 2 : wv;    // i->0, f->1, o->2
            ex[t & 1][slot][hi * 4 + 0][lo] = sigmoidf_(p0);
            ex[t & 1][slot][hi * 4 + 1][lo] = sigmoidf_(p1);
            ex[t & 1][slot][hi * 4 + 2][lo] = sigmoidf_(p2);
            ex[t & 1][slot][hi * 4 + 3][lo] = sigmoidf_(p3);
        }
        __syncthreads();                         // ex visible to wave2

        if (wv == 2) {
            const int jj = J + lo;
            #pragma unroll
            for (int r = 0; r < 4; ++r) {
                const int row = hi * 4 + r;
                const float pv = (r == 0) ? p0 : (r == 1) ? p1 : (r == 2) ? p2 : p3;
                const float i_ = ex[t & 1][0][row][lo];
                const float f_ = ex[t & 1][1][row][lo];
                const float o_ = ex[t & 1][2][row][lo];
                float& cr = (r == 0) ? cr0 : (r == 1) ? cr1 : (r == 2) ? cr2 : cr3;
                cr = f_ * cr + i_ * fmaxf(pv, 0.f);
                const float hn = o_ * fmaxf(cr, 0.f);
                const ushortT hv = f2bf(hn);
                const int b = b0 + row;
                hwr[(size_t)b * U_ + jj] = hv;
                if (hseqX && t == CH - 1) h0[(size_t)b * U_ + jj] = hv;  // carry
            }
            if (lane == 0)
                __hip_atomic_store(&gflag[wgj], (unsigned)(t + 1), __ATOMIC_RELEASE,
                                   __HIP_MEMORY_SCOPE_AGENT);
        }
    }

    if (wv == 2) {
        cst[(size_t)(b0 + hi * 4 + 0) * U_ + J + lo] = cr0;
        cst[(size_t)(b0 + hi * 4 + 1) * U_ + J + lo] = cr1;
        cst[(size_t)(b0 + hi * 4 + 2) * U_ + J + lo] = cr2;
        cst[(size_t)(b0 + hi * 4 + 3) * U_ + J + lo] = cr3;
    }
}

// ---------------------------------------------------------------------------
// Head: out[b] = sigmoid( relu(h2[b,:] @ Wd + bd) @ Wc + bc ), h2 bf16 [128][256]
// ---------------------------------------------------------------------------
__global__ __launch_bounds__(64) void head_kernel(
    const ushortT* __restrict__ h2,
    const float* __restrict__ Wd,
    const float* __restrict__ bd,
    const float* __restrict__ Wc,
    const float* __restrict__ bc,
    float* __restrict__ out)
{
    const int b = blockIdx.x;
    const int j = threadIdx.x;          // 0..63
    float a = bd[j];
    const ushortT* hrow = h2 + (size_t)b * NU2;
    #pragma unroll 4
    for (int k = 0; k < NU2; ++k)
        a += bf2f(hrow[k]) * Wd[(size_t)k * NDENSE + j];
    a = fmaxf(a, 0.f) * Wc[j];
    #pragma unroll
    for (int off = 32; off > 0; off >>= 1)
        a += __shfl_down(a, off);
    if (j == 0)
        out[b] = 1.f / (1.f + expf(-(a + bc[0])));
}

// ---------------------------------------------------------------------------
extern "C" void kernel_launch(void* const* d_in, const int* in_sizes, int n_in,
                              void* d_out, int out_size, void* d_ws, size_t ws_size,
                              hipStream_t stream)
{
    const int*   tokens = (const int*)  d_in[0];
    const float* emb    = (const float*)d_in[1];
    const float* W0     = (const float*)d_in[2];
    const float* Ur0    = (const float*)d_in[3];
    const float* b0v    = (const float*)d_in[4];
    const float* W1     = (const float*)d_in[5];
    const float* Ur1    = (const float*)d_in[6];
    const float* b1v    = (const float*)d_in[7];
    const float* W2     = (const float*)d_in[8];
    const float* Ur2    = (const float*)d_in[9];
    const float* b2v    = (const float*)d_in[10];
    const float* Wd     = (const float*)d_in[11];
    const float* bd     = (const float*)d_in[12];
    const float* Wc     = (const float*)d_in[13];
    const float* bc     = (const float*)d_in[14];
    float* out = (float*)d_out;

    auto need = [](size_t ch) -> size_t {
        return ch * 2048 * 128 * 4            // xgT (worst layer, f32)
             + ch * 128 * (256 + 512) * 2     // hseqX slabs (bf16)
             + (size_t)(16 << 20);            // converts + states + slack
    };
    size_t CH = 128;
    while (CH > 8 && need(CH) > ws_size) CH >>= 1;
    const int nc = SEQT / (int)CH;

    char* p = (char*)d_ws;
    auto alloc = [&](size_t bytes) -> char* {
        char* q = p; p += (bytes + 255) & ~(size_t)255; return q;
    };
    float*   xgT   = (float*)  alloc(CH * 2048 * 128 * 4);
    ushortT* hs0   = (ushortT*)alloc(CH * 128 * NU0 * 2);
    ushortT* hs1   = (ushortT*)alloc(CH * 128 * NU1 * 2);
    ushortT* WbfT0 = (ushortT*)alloc((size_t)4 * NU0 * KP0 * 2);
    ushortT* WbfT1 = (ushortT*)alloc((size_t)4 * NU1 * NU0 * 2);
    ushortT* WbfT2 = (ushortT*)alloc((size_t)4 * NU2 * NU1 * 2);
    ushortT* embbf = (ushortT*)alloc((size_t)VOCABN * KP0 * 2);
    ushortT* h0A   = (ushortT*)alloc(128 * NU0 * 2);
    ushortT* h1A   = (ushortT*)alloc(128 * NU1 * 2);
    ushortT* h2A   = (ushortT*)alloc(128 * NU2 * 2);
    ushortT* h2B   = (ushortT*)alloc(128 * NU2 * 2);
    float*   c0    = (float*)  alloc(128 * NU0 * 4);
    float*   c1    = (float*)  alloc(128 * NU1 * 4);
    float*   c2    = (float*)  alloc(128 * NU2 * 4);
    unsigned* flg  = (unsigned*)alloc(16384);

    hipMemsetAsync(flg, 0, 16384, stream);

    // one-time weight/embedding converts
    convert_WT<<<512, 256, 0, stream>>>(W0, WbfT0, EMB_D, 4 * NU0, KP0, 4 * NU0 * KP0);
    convert_WT<<<512, 256, 0, stream>>>(W1, WbfT1, NU0, 4 * NU1, NU0, 4 * NU1 * NU0);
    convert_WT<<<512, 256, 0, stream>>>(W2, WbfT2, NU1, 4 * NU2, NU1, 4 * NU2 * NU1);
    convert_emb<<<1024, 256, 0, stream>>>(emb, embbf);

    auto kA = lstm_mfma<NU0>;   // layers 0 and 2
    auto kB = lstm_mfma<NU1>;

    for (int ci = 0; ci < nc; ++ci) {
        const int t0 = ci * (int)CH;
        int init = (ci == 0) ? 1 : 0;
        int ch = (int)CH;

        // ---- layer 0 ----
        gemm_mfma<0><<<dim3((int)CH, 8), 256, 0, stream>>>(
            embbf, tokens, t0, WbfT0, b0v, xgT, 4 * NU0, KP0);
        {
            const float* xp = xgT; const float* up = Ur0;
            ushortT *ha = h0A, *hb = h0A, *hq = hs0;
            float* cp = c0;
            unsigned* fq = flg + (size_t)(ci * 3 + 0) * 256;
            void* args[] = {&xp, &up, &ha, &hb, &cp, &hq, &fq, &ch, &init};
            hipLaunchCooperativeKernel((void*)kA, dim3(8 * (NU0 / 16)), dim3(256),
                                       args, 0, stream);
        }
        // ---- layer 1 ----
        gemm_mfma<1><<<dim3((int)CH, 16), 256, 0, stream>>>(
            hs0, nullptr, 0, WbfT1, b1v, xgT, 4 * NU1, NU0);
        {
            const float* xp = xgT; const float* up = Ur1;
            ushortT *ha = h1A, *hb = h1A, *hq = hs1;
            float* cp = c1;
            unsigned* fq = flg + (size_t)(ci * 3 + 1) * 256;
            void* args[] = {&xp, &up, &ha, &hb, &cp, &hq, &fq, &ch, &init};
            hipLaunchCooperativeKernel((void*)kB, dim3(8 * (NU1 / 16)), dim3(256),
                                       args, 0, stream);
        }
        // ---- layer 2 ----
        gemm_mfma<1><<<dim3((int)CH, 8), 256, 0, stream>>>(
            hs1, nullptr, 0, WbfT2, b2v, xgT, 4 * NU2, NU1);
        {
            const float* xp = xgT; const float* up = Ur2;
            ushortT *ha = h2A, *hb = h2B, *hq = nullptr;
            float* cp = c2;
            unsigned* fq = flg + (size_t)(ci * 3 + 2) * 256;
            void* args[] = {&xp, &up, &ha, &hb, &cp, &hq, &fq, &ch, &init};
            hipLaunchCooperativeKernel((void*)kA, dim3(8 * (NU2 / 16)), dim3(256),
                                       args, 0, stream);
        }
    }

    // CH even -> layer-2 final h in parity-0 buffer (h2A)
    head_kernel<<<BATCH, 64, 0, stream>>>(h2A, Wd, bd, Wc, bc, out);
}

// Round 7
// 7771.709 us; speedup vs baseline: 2.1384x; 2.1384x over previous
//
#include <hip/hip_runtime.h>
#include <cstdint>
#include <cstddef>

#define BATCH  128
#define SEQT   512
#define EMB_D  300
#define VOCABN 5000
#define KP0    320          // EMB_D padded to mult of 32
#define NU0    256
#define NU1    512
#define NU2    256
#define NDENSE 64

typedef unsigned short ushortT;
typedef __attribute__((ext_vector_type(8))) short bf16x8;
typedef __attribute__((ext_vector_type(8))) unsigned short u16x8;
typedef __attribute__((ext_vector_type(4))) float f32x4;

static __device__ __forceinline__ unsigned short f2bf(float x) {
    union { float f; unsigned u; } v; v.f = x;
    const unsigned r = v.u + 0x7FFFu + ((v.u >> 16) & 1u);
    return (unsigned short)(r >> 16);
}
static __device__ __forceinline__ float bf2f(unsigned short b) {
    union { unsigned u; float f; } v; v.u = ((unsigned)b) << 16;
    return v.f;
}
static __device__ __forceinline__ float sigmoidf_(float x) {
    return 1.f / (1.f + __expf(-x));
}

// ---------------------------------------------------------------------------
// One-time converts: W [K][NG] f32 -> WbfT [NG][KP] bf16 (transposed, padded);
// emb [VOCAB][300] f32 -> embbf [VOCAB][KP0] bf16 (padded).
// ---------------------------------------------------------------------------
__global__ __launch_bounds__(256) void convert_WT(
    const float* __restrict__ W, ushortT* __restrict__ WbfT,
    int K, int NG, int KP, int total)
{
    for (int idx = blockIdx.x * 256 + threadIdx.x; idx < total; idx += gridDim.x * 256) {
        const int m = idx / KP, k = idx - m * KP;
        WbfT[idx] = (k < K) ? f2bf(W[(size_t)k * NG + m]) : (ushortT)0;
    }
}
__global__ __launch_bounds__(256) void convert_emb(
    const float* __restrict__ emb, ushortT* __restrict__ embbf)
{
    const int total = VOCABN * KP0;
    for (int idx = blockIdx.x * 256 + threadIdx.x; idx < total; idx += gridDim.x * 256) {
        const int v = idx / KP0, k = idx - v * KP0;
        embbf[idx] = (k < EMB_D) ? f2bf(emb[(size_t)v * EMB_D + k]) : (ushortT)0;
    }
}

// ---------------------------------------------------------------------------
// MFMA GEMM: xgT[t][g][m][b16] = sum_k WbfT[m][k] * x_t[b][k] + bias[m]
// with b = g*16 + b16. 16x16x32 bf16 MFMA, 128Mx128N tile, BK=32, 4 waves,
// XOR-swizzled LDS. MODE 0: x gathered from embbf; MODE 1: x = hseqX slab t.
// ---------------------------------------------------------------------------
template<int MODE>
__global__ __launch_bounds__(256) void gemm_mfma(
    const ushortT* __restrict__ Bsrc,
    const int*   __restrict__ tokens, int t0,
    const ushortT* __restrict__ WbfT,   // [NG][KP]
    const float* __restrict__ bias,     // [NG]
    float* __restrict__ xgT,            // [CH][8][NG][16]
    int NG, int KP)
{
    __shared__ ushortT Wl[128][32];
    __shared__ ushortT Xl[128][32];
    __shared__ int tokL[128];

    const int tid = threadIdx.x;
    const int t   = blockIdx.x;
    const int m0  = blockIdx.y * 128;
    const int wv  = tid >> 6;
    const int lane = tid & 63;
    const int lo  = lane & 15;
    const int hi  = lane >> 4;

    if (MODE == 0) {
        if (tid < 128) tokL[tid] = tokens[tid * SEQT + t0 + t];
        __syncthreads();
    }

    f32x4 acc[2][8];
    #pragma unroll
    for (int s = 0; s < 2; ++s)
        #pragma unroll
        for (int n = 0; n < 8; ++n)
            acc[s][n] = f32x4{0.f, 0.f, 0.f, 0.f};

    for (int k0 = 0; k0 < KP; k0 += 32) {
        #pragma unroll
        for (int it = 0; it < 2; ++it) {
            const int idx = tid + it * 256;          // 0..511
            const int row = idx >> 2, gq = idx & 3;
            const int gs  = gq ^ ((row >> 1) & 3);
            *(u16x8*)&Wl[row][gs * 8] =
                *(const u16x8*)(WbfT + (size_t)(m0 + row) * KP + k0 + gq * 8);
            const ushortT* xs;
            if (MODE == 0) xs = Bsrc + (size_t)tokL[row] * KP + k0 + gq * 8;
            else           xs = Bsrc + ((size_t)t * 128 + row) * KP + k0 + gq * 8;
            *(u16x8*)&Xl[row][gs * 8] = *(const u16x8*)xs;
        }
        __syncthreads();

        bf16x8 bfr[8];
        #pragma unroll
        for (int n = 0; n < 8; ++n) {
            const int row = n * 16 + lo;
            bfr[n] = *(const bf16x8*)&Xl[row][(hi ^ ((row >> 1) & 3)) * 8];
        }
        #pragma unroll
        for (int s = 0; s < 2; ++s) {
            const int row = wv * 32 + s * 16 + lo;
            const bf16x8 a = *(const bf16x8*)&Wl[row][(hi ^ ((row >> 1) & 3)) * 8];
            #pragma unroll
            for (int n = 0; n < 8; ++n)
                acc[s][n] = __builtin_amdgcn_mfma_f32_16x16x32_bf16(a, bfr[n], acc[s][n], 0, 0, 0);
        }
        __syncthreads();
    }

    #pragma unroll
    for (int s = 0; s < 2; ++s) {
        #pragma unroll
        for (int j = 0; j < 4; ++j) {
            const int m = m0 + wv * 32 + s * 16 + hi * 4 + j;
            const float bi = bias[m];
            #pragma unroll
            for (int n = 0; n < 8; ++n)
                xgT[(((size_t)t * 8 + n) * NG + m) * 16 + lo] = acc[s][n][j] + bi;
        }
    }
}

// ---------------------------------------------------------------------------
// MFMA recurrence, small sync domains. 8 groups (g = blockIdx.x & 7, XCD-
// local) x 16 batch rows. WG = 512 threads (8 waves), owns JCOLS h-cols:
// wave w -> gate (w&3), col-half (w>>2). U cols persistent in bf16 B-frags
// (128 VGPR/thread). Per step: wave0 polls the group's 2*WPG flags (one
// wave polls, barrier broadcasts); h tile staged global->LDS once
// (XOR-swizzled granules, conflict-free b128 reads); MFMA; gate exchange
// via LDS; c-waves (gate 2) update c,h, store h, release-store their flag
// (orders own h stores). xg register-prefetched 1 step ahead.
// ---------------------------------------------------------------------------
template<int U_, int JCOLS>
__global__ __launch_bounds__(512, 2) void lstm_mfma(
    const float* __restrict__ xgT,     // [CH][8][4U][16]
    const float* __restrict__ Umat,    // [U][4U] gates i,f,c,o
    ushortT* __restrict__ h0,          // carry / parity0 [128][U] bf16
    ushortT* __restrict__ h1,          // parity1 (layer-2 ping-pong)
    float* __restrict__ cst,           // [128][U]
    ushortT* __restrict__ hseqX,       // [CH][128][U] bf16 or nullptr
    unsigned* __restrict__ flags,      // [8][32], zeroed before launch
    int CH, int init)
{
    constexpr int NG    = 4 * U_;
    constexpr int WPG   = U_ / JCOLS;   // WGs per group
    constexpr int JH    = JCOLS / 2;    // j-cols per col-half
    constexpr int TILES = JH / 16;      // 16-col tiles per wave
    constexpr int KT    = U_ / 32;      // MFMA K-tiles
    constexpr int GR    = U_ / 8;       // 16B granules per h row
    constexpr int NFLAG = 2 * WPG;

    __shared__ ushortT hstage[16 * U_];
    __shared__ float ex[3][2][JH][17];  // [slot][colhalf][j][b]

    const int tid  = threadIdx.x;
    const int w    = tid >> 6;
    const int lane = tid & 63;
    const int lo   = lane & 15;
    const int hi   = lane >> 4;
    const int g4   = w & 3;             // gate i,f,c,o
    const int chh  = w >> 2;            // col half
    const int grp  = blockIdx.x & 7;    // XCD-local group
    const int wgj  = blockIdx.x >> 3;
    const int b0   = grp * 16;
    const int J    = wgj * JCOLS;
    const size_t S = (size_t)128 * U_;
    unsigned* gflag = flags + grp * 32;

    int gc[TILES];
    #pragma unroll
    for (int tl = 0; tl < TILES; ++tl)
        gc[tl] = g4 * U_ + J + chh * JH + tl * 16 + lo;

    // ---- persistent B-fragments: U[:, gc[tl]] in bf16 ----
    bf16x8 bfr[TILES][KT];
    #pragma unroll
    for (int tl = 0; tl < TILES; ++tl) {
        #pragma unroll
        for (int kt = 0; kt < KT; ++kt) {
            const float* up = Umat + (size_t)(kt * 32 + hi * 8) * NG + gc[tl];
            bf16x8 v;
            #pragma unroll
            for (int i = 0; i < 8; ++i) v[i] = (short)f2bf(up[(size_t)i * NG]);
            bfr[tl][kt] = v;
        }
    }

    // ---- c state (c-waves own (b = b0+hi*4+r, j = gc[tl]-2*U)) ----
    float creg[TILES][4];
    #pragma unroll
    for (int tl = 0; tl < TILES; ++tl)
        #pragma unroll
        for (int r = 0; r < 4; ++r) creg[tl][r] = 0.f;
    if (!init && g4 == 2) {
        #pragma unroll
        for (int tl = 0; tl < TILES; ++tl)
            #pragma unroll
            for (int r = 0; r < 4; ++r)
                creg[tl][r] = cst[(size_t)(b0 + hi * 4 + r) * U_ + (gc[tl] - 2 * U_)];
    }

    // ---- xg prefetch (t = 0) ----
    float4 xv[TILES];
    #pragma unroll
    for (int tl = 0; tl < TILES; ++tl)
        xv[tl] = *(const float4*)(xgT + ((size_t)grp * NG + gc[tl]) * 16 + hi * 4);

    for (int t = 0; t < CH; ++t) {
        float4 xvn[TILES];
        #pragma unroll
        for (int tl = 0; tl < TILES; ++tl) xvn[tl] = xv[tl];
        if (t + 1 < CH) {
            const size_t tb = (size_t)(t + 1) * 8 * NG * 16;
            #pragma unroll
            for (int tl = 0; tl < TILES; ++tl)
                xvn[tl] = *(const float4*)(xgT + tb + ((size_t)grp * NG + gc[tl]) * 16 + hi * 4);
        }

        const bool have_h = !(init && t == 0);
        if (have_h) {
            if (t > 0 && w == 0) {
                const unsigned tgt = (unsigned)t;
                const int fidx = lane & (NFLAG - 1);
                int guard = 0;
                for (;;) {
                    const unsigned v = __hip_atomic_load(&gflag[fidx], __ATOMIC_RELAXED,
                                                         __HIP_MEMORY_SCOPE_AGENT);
                    if (__all((int)(v >= tgt))) break;
                    __builtin_amdgcn_s_sleep(2);
                    if (++guard > (1 << 22)) break;
                }
                (void)__hip_atomic_load(&gflag[0], __ATOMIC_ACQUIRE,
                                        __HIP_MEMORY_SCOPE_AGENT);
            }
            __syncthreads();   // B1: h ready

            // stage h tile [16][U] -> LDS (swizzled 16B granules)
            const ushortT* hsrc;
            if (hseqX) hsrc = t ? (hseqX + (size_t)(t - 1) * S) : h0;
            else       hsrc = (t == 0) ? h0 : (((t - 1) & 1) ? h0 : h1);
            #pragma unroll
            for (int i = tid; i < 16 * GR; i += 512) {
                const int row = i / GR, gi = i % GR;
                const int gs = gi ^ (row & 7);
                *(u16x8*)&hstage[(row * GR + gs) * 8] =
                    *(const u16x8*)(hsrc + (size_t)(b0 + row) * U_ + gi * 8);
            }
            __syncthreads();   // B2: h staged
        }

        f32x4 acc[TILES];
        #pragma unroll
        for (int tl = 0; tl < TILES; ++tl) acc[tl] = f32x4{0.f, 0.f, 0.f, 0.f};
        if (have_h) {
            #pragma unroll
            for (int kt = 0; kt < KT; ++kt) {
                const int gs = (kt * 4 + hi) ^ (lo & 7);
                const bf16x8 a = *(const bf16x8*)&hstage[(lo * GR + gs) * 8];
                #pragma unroll
                for (int tl = 0; tl < TILES; ++tl)
                    acc[tl] = __builtin_amdgcn_mfma_f32_16x16x32_bf16(a, bfr[tl][kt], acc[tl], 0, 0, 0);
            }
        }

        float p[TILES][4];
        #pragma unroll
        for (int tl = 0; tl < TILES; ++tl) {
            p[tl][0] = acc[tl][0] + xv[tl].x;
            p[tl][1] = acc[tl][1] + xv[tl].y;
            p[tl][2] = acc[tl][2] + xv[tl].z;
            p[tl][3] = acc[tl][3] + xv[tl].w;
            xv[tl] = xvn[tl];
        }

        if (g4 != 2) {
            const int slot = (g4 == 3) ? 2 : g4;    // i->0, f->1, o->2
            #pragma unroll
            for (int tl = 0; tl < TILES; ++tl)
                #pragma unroll
                for (int r = 0; r < 4; ++r)
                    ex[slot][chh][tl * 16 + lo][hi * 4 + r] = sigmoidf_(p[tl][r]);
        }
        __syncthreads();       // B3: gates exchanged

        if (g4 == 2) {
            ushortT* hwr;
            if (hseqX) hwr = hseqX + (size_t)t * S;
            else       hwr = (t & 1) ? h0 : h1;
            #pragma unroll
            for (int tl = 0; tl < TILES; ++tl) {
                const int jh = tl * 16 + lo;
                const int j  = gc[tl] - 2 * U_;
                #pragma unroll
                for (int r = 0; r < 4; ++r) {
                    const int row = hi * 4 + r;
                    const float i_ = ex[0][chh][jh][row];
                    const float f_ = ex[1][chh][jh][row];
                    const float o_ = ex[2][chh][jh][row];
                    creg[tl][r] = f_ * creg[tl][r] + i_ * fmaxf(p[tl][r], 0.f);
                    const float hn = o_ * fmaxf(creg[tl][r], 0.f);
                    const ushortT hv = f2bf(hn);
                    hwr[(size_t)(b0 + row) * U_ + j] = hv;
                    if (hseqX && t == CH - 1) h0[(size_t)(b0 + row) * U_ + j] = hv;
                }
            }
            if (lane == 0)
                __hip_atomic_store(&gflag[wgj * 2 + chh], (unsigned)(t + 1),
                                   __ATOMIC_RELEASE, __HIP_MEMORY_SCOPE_AGENT);
        }
    }

    if (g4 == 2) {
        #pragma unroll
        for (int tl = 0; tl < TILES; ++tl)
            #pragma unroll
            for (int r = 0; r < 4; ++r)
                cst[(size_t)(b0 + hi * 4 + r) * U_ + (gc[tl] - 2 * U_)] = creg[tl][r];
    }
}

// ---------------------------------------------------------------------------
// Head: out[b] = sigmoid( relu(h2[b,:] @ Wd + bd) @ Wc + bc ), h2 bf16 [128][256]
// ---------------------------------------------------------------------------
__global__ __launch_bounds__(64) void head_kernel(
    const ushortT* __restrict__ h2,
    const float* __restrict__ Wd,
    const float* __restrict__ bd,
    const float* __restrict__ Wc,
    const float* __restrict__ bc,
    float* __restrict__ out)
{
    const int b = blockIdx.x;
    const int j = threadIdx.x;          // 0..63
    float a = bd[j];
    const ushortT* hrow = h2 + (size_t)b * NU2;
    #pragma unroll 4
    for (int k = 0; k < NU2; ++k)
        a += bf2f(hrow[k]) * Wd[(size_t)k * NDENSE + j];
    a = fmaxf(a, 0.f) * Wc[j];
    #pragma unroll
    for (int off = 32; off > 0; off >>= 1)
        a += __shfl_down(a, off);
    if (j == 0)
        out[b] = 1.f / (1.f + expf(-(a + bc[0])));
}

// ---------------------------------------------------------------------------
extern "C" void kernel_launch(void* const* d_in, const int* in_sizes, int n_in,
                              void* d_out, int out_size, void* d_ws, size_t ws_size,
                              hipStream_t stream)
{
    const int*   tokens = (const int*)  d_in[0];
    const float* emb    = (const float*)d_in[1];
    const float* W0     = (const float*)d_in[2];
    const float* Ur0    = (const float*)d_in[3];
    const float* b0v    = (const float*)d_in[4];
    const float* W1     = (const float*)d_in[5];
    const float* Ur1    = (const float*)d_in[6];
    const float* b1v    = (const float*)d_in[7];
    const float* W2     = (const float*)d_in[8];
    const float* Ur2    = (const float*)d_in[9];
    const float* b2v    = (const float*)d_in[10];
    const float* Wd     = (const float*)d_in[11];
    const float* bd     = (const float*)d_in[12];
    const float* Wc     = (const float*)d_in[13];
    const float* bc     = (const float*)d_in[14];
    float* out = (float*)d_out;

    auto need = [](size_t ch) -> size_t {
        return ch * 2048 * 128 * 4            // xgT (worst layer, f32)
             + ch * 128 * (256 + 512) * 2     // hseqX slabs (bf16)
             + (size_t)(16 << 20);            // converts + states + slack
    };
    size_t CH = 128;
    while (CH > 8 && need(CH) > ws_size) CH >>= 1;
    const int nc = SEQT / (int)CH;

    char* p = (char*)d_ws;
    auto alloc = [&](size_t bytes) -> char* {
        char* q = p; p += (bytes + 255) & ~(size_t)255; return q;
    };
    float*   xgT   = (float*)  alloc(CH * 2048 * 128 * 4);
    ushortT* hs0   = (ushortT*)alloc(CH * 128 * NU0 * 2);
    ushortT* hs1   = (ushortT*)alloc(CH * 128 * NU1 * 2);
    ushortT* WbfT0 = (ushortT*)alloc((size_t)4 * NU0 * KP0 * 2);
    ushortT* WbfT1 = (ushortT*)alloc((size_t)4 * NU1 * NU0 * 2);
    ushortT* WbfT2 = (ushortT*)alloc((size_t)4 * NU2 * NU1 * 2);
    ushortT* embbf = (ushortT*)alloc((size_t)VOCABN * KP0 * 2);
    ushortT* h0A   = (ushortT*)alloc(128 * NU0 * 2);
    ushortT* h1A   = (ushortT*)alloc(128 * NU1 * 2);
    ushortT* h2A   = (ushortT*)alloc(128 * NU2 * 2);
    ushortT* h2B   = (ushortT*)alloc(128 * NU2 * 2);
    float*   c0    = (float*)  alloc(128 * NU0 * 4);
    float*   c1    = (float*)  alloc(128 * NU1 * 4);
    float*   c2    = (float*)  alloc(128 * NU2 * 4);
    unsigned* flg  = (unsigned*)alloc(16384);

    hipMemsetAsync(flg, 0, 16384, stream);

    // one-time weight/embedding converts
    convert_WT<<<512, 256, 0, stream>>>(W0, WbfT0, EMB_D, 4 * NU0, KP0, 4 * NU0 * KP0);
    convert_WT<<<512, 256, 0, stream>>>(W1, WbfT1, NU0, 4 * NU1, NU0, 4 * NU1 * NU0);
    convert_WT<<<512, 256, 0, stream>>>(W2, WbfT2, NU1, 4 * NU2, NU1, 4 * NU2 * NU1);
    convert_emb<<<1024, 256, 0, stream>>>(emb, embbf);

    auto kA = lstm_mfma<NU0, 128>;   // WPG=2: layers 0 and 2, grid 16
    auto kB = lstm_mfma<NU1, 64>;    // WPG=8: layer 1, grid 64

    for (int ci = 0; ci < nc; ++ci) {
        const int t0 = ci * (int)CH;
        int init = (ci == 0) ? 1 : 0;
        int ch = (int)CH;

        // ---- layer 0 ----
        gemm_mfma<0><<<dim3((int)CH, 8), 256, 0, stream>>>(
            embbf, tokens, t0, WbfT0, b0v, xgT, 4 * NU0, KP0);
        {
            const float* xp = xgT; const float* up = Ur0;
            ushortT *ha = h0A, *hb = h0A, *hq = hs0;
            float* cp = c0;
            unsigned* fq = flg + (size_t)(ci * 3 + 0) * 256;
            void* args[] = {&xp, &up, &ha, &hb, &cp, &hq, &fq, &ch, &init};
            hipLaunchCooperativeKernel((void*)kA, dim3(16), dim3(512), args, 0, stream);
        }
        // ---- layer 1 ----
        gemm_mfma<1><<<dim3((int)CH, 16), 256, 0, stream>>>(
            hs0, nullptr, 0, WbfT1, b1v, xgT, 4 * NU1, NU0);
        {
            const float* xp = xgT; const float* up = Ur1;
            ushortT *ha = h1A, *hb = h1A, *hq = hs1;
            float* cp = c1;
            unsigned* fq = flg + (size_t)(ci * 3 + 1) * 256;
            void* args[] = {&xp, &up, &ha, &hb, &cp, &hq, &fq, &ch, &init};
            hipLaunchCooperativeKernel((void*)kB, dim3(64), dim3(512), args, 0, stream);
        }
        // ---- layer 2 ----
        gemm_mfma<1><<<dim3((int)CH, 8), 256, 0, stream>>>(
            hs1, nullptr, 0, WbfT2, b2v, xgT, 4 * NU2, NU1);
        {
            const float* xp = xgT; const float* up = Ur2;
            ushortT *ha = h2A, *hb = h2B, *hq = nullptr;
            float* cp = c2;
            unsigned* fq = flg + (size_t)(ci * 3 + 2) * 256;
            void* args[] = {&xp, &up, &ha, &hb, &cp, &hq, &fq, &ch, &init};
            hipLaunchCooperativeKernel((void*)kA, dim3(16), dim3(512), args, 0, stream);
        }
    }

    // CH even -> layer-2 final h lands in h0 path (h2A)
    head_kernel<<<BATCH, 64, 0, stream>>>(h2A, Wd, bd, Wc, bc, out);
}

// Round 8
// 5320.459 us; speedup vs baseline: 3.1237x; 1.4607x over previous
//
#include <hip/hip_runtime.h>
#include <cstdint>
#include <cstddef>

#define BATCH  128
#define SEQT   512
#define EMB_D  300
#define VOCABN 5000
#define KP0    320
#define NU0    256
#define NU1    512
#define NU2    256
#define NDENSE 64
#define RING   16
#define LIM    (1 << 19)

typedef unsigned short ushortT;
typedef __attribute__((ext_vector_type(8))) short bf16x8;
typedef __attribute__((ext_vector_type(8))) unsigned short u16x8;
typedef __attribute__((ext_vector_type(4))) unsigned short u16x4;
typedef __attribute__((ext_vector_type(4))) float f32x4;

#define AGT __HIP_MEMORY_SCOPE_AGENT

static __device__ __forceinline__ unsigned short f2bf(float x) {
    union { float f; unsigned u; } v; v.f = x;
    const unsigned r = v.u + 0x7FFFu + ((v.u >> 16) & 1u);
    return (unsigned short)(r >> 16);
}
static __device__ __forceinline__ float bf2f(unsigned short b) {
    union { unsigned u; float f; } v; v.u = ((unsigned)b) << 16;
    return v.f;
}
static __device__ __forceinline__ float sigmoidf_(float x) {
    return 1.f / (1.f + __expf(-x));
}
static __device__ __forceinline__ unsigned ald(const unsigned* p) {
    return __hip_atomic_load((unsigned*)p, __ATOMIC_RELAXED, AGT);
}

// ---------------------------------------------------------------------------
// One-time converts (unchanged from round 7)
// ---------------------------------------------------------------------------
__global__ __launch_bounds__(256) void convert_WT(
    const float* __restrict__ W, ushortT* __restrict__ WbfT,
    int K, int NG, int KP, int total)
{
    for (int idx = blockIdx.x * 256 + threadIdx.x; idx < total; idx += gridDim.x * 256) {
        const int m = idx / KP, k = idx - m * KP;
        WbfT[idx] = (k < K) ? f2bf(W[(size_t)k * NG + m]) : (ushortT)0;
    }
}
__global__ __launch_bounds__(256) void convert_emb(
    const float* __restrict__ emb, ushortT* __restrict__ embbf)
{
    const int total = VOCABN * KP0;
    for (int idx = blockIdx.x * 256 + threadIdx.x; idx < total; idx += gridDim.x * 256) {
        const int v = idx / KP0, k = idx - v * KP0;
        embbf[idx] = (k < EMB_D) ? f2bf(emb[(size_t)v * EMB_D + k]) : (ushortT)0;
    }
}

// ---------------------------------------------------------------------------
// Megakernel args
// ---------------------------------------------------------------------------
struct MegaArgs {
    const int* tokens;
    const ushortT* embbf;
    const ushortT *W0T, *W1T, *W2T;     // [NG][KP] bf16
    const float *b0, *b1, *b2;          // [NG]
    const float *U0, *U1, *U2;          // [U][4U] f32
    ushortT *xg0, *xg1, *xg2;           // rings [RING][8][NG][16] bf16
    ushortT *h0r, *h1r, *h2r;           // rings [RING][128][U] bf16
    unsigned *F0, *F1, *F2, *X0, *X1, *X2;  // flags, 16-word stride each
};

// ---------------------------------------------------------------------------
// Recurrence role (round-7 structure + ring buffers + combined per-lane poll).
// WG=512thr: wave w -> gate (w&3), col-half (w>>2); group grp=rid&7 owns 16 b.
// One flag per WG (release after all-wave vmcnt drain + barrier).
// Poll lanes: [0,WPG) own-group h flags >= t; [WPG,WPG+NX) own xg mtile flags
// >= t+1; next nguard lanes downstream-consumer ring guard >= t-(RING-1).
// ---------------------------------------------------------------------------
template<int U_, int JCOLS>
__device__ void rec_role(
    int rid,
    const float* __restrict__ Umat,
    const ushortT* __restrict__ xgring,
    ushortT* __restrict__ hring,
    unsigned* Fown, unsigned* Xown, int xph,
    unsigned* Xguard, int nguard,
    char* smem)
{
    constexpr int NGu   = 4 * U_;
    constexpr int WPG   = U_ / JCOLS;
    constexpr int JH    = JCOLS / 2;
    constexpr int TILES = JH / 16;
    constexpr int KT    = U_ / 32;
    constexpr int GR    = U_ / 8;
    constexpr int NX    = JCOLS / 16;      // own xg mtile flags (4*JCOLS/64)
    constexpr int SG    = (JCOLS >= 64) ? (JCOLS / 64) : 1;

    ushortT* hstage = (ushortT*)smem;                      // [16][U]
    float*   ex     = (float*)(smem + 2 * 16 * U_);        // [3][2][JH][17]

    const int tid = threadIdx.x, w = tid >> 6, lane = tid & 63;
    const int lo = lane & 15, hi = lane >> 4;
    const int g4 = w & 3, chh = w >> 2;
    const int grp = rid & 7, wgj = rid >> 3;
    const int b0 = grp * 16, J = wgj * JCOLS;
    const size_t S = (size_t)128 * U_;

    int gc[TILES];
    #pragma unroll
    for (int tl = 0; tl < TILES; ++tl)
        gc[tl] = g4 * U_ + J + chh * JH + tl * 16 + lo;

    // persistent B-fragments (U cols, bf16)
    bf16x8 bfr[TILES][KT];
    #pragma unroll
    for (int tl = 0; tl < TILES; ++tl)
        #pragma unroll
        for (int kt = 0; kt < KT; ++kt) {
            const float* up = Umat + (size_t)(kt * 32 + hi * 8) * NGu + gc[tl];
            bf16x8 v;
            #pragma unroll
            for (int i = 0; i < 8; ++i) v[i] = (short)f2bf(up[(size_t)i * NGu]);
            bfr[tl][kt] = v;
        }

    float creg[TILES][4];
    #pragma unroll
    for (int tl = 0; tl < TILES; ++tl)
        #pragma unroll
        for (int r = 0; r < 4; ++r) creg[tl][r] = 0.f;

    // poll-lane static setup
    int mt_l = 0;
    if (lane >= WPG && lane < WPG + NX) {
        const int i = lane - WPG;
        const int g = i / SG, s = i - g * SG;
        mt_l = g * (U_ / 64) + J / 64 + s;
    }

    for (int t = 0; t < SEQT; ++t) {
        if (w == 0) {
            int guard = 0; bool ok;
            do {
                bool pred = true;
                if (lane < WPG)
                    pred = (int)ald(&Fown[(grp * WPG + lane) * 16]) >= t;
                else if (lane < WPG + NX)
                    pred = (int)ald(&Xown[(mt_l * xph + ((xph == 2) ? (t & 1) : 0)) * 16]) >= t + 1;
                else if (lane < WPG + NX + nguard)
                    pred = (int)ald(&Xguard[(lane - WPG - NX) * 16]) >= t - (RING - 1);
                ok = __all(pred);
                if (!ok) __builtin_amdgcn_s_sleep(1);
            } while (!ok && ++guard < LIM);
            if (lane == 0)
                (void)__hip_atomic_load(&Fown[0], __ATOMIC_ACQUIRE, AGT);
        }
        __syncthreads();   // B1: deps satisfied

        // xg loads (bf16, ring slab t)
        u16x4 xr[TILES];
        const size_t xb = (size_t)((t & (RING - 1)) * 8 + grp) * NGu;
        #pragma unroll
        for (int tl = 0; tl < TILES; ++tl)
            xr[tl] = *(const u16x4*)(xgring + (xb + gc[tl]) * 16 + hi * 4);

        if (t > 0) {
            const ushortT* hsrc = hring + (size_t)((t - 1) & (RING - 1)) * S;
            for (int i = tid; i < 16 * GR; i += 512) {
                const int row = i / GR, gi = i - row * GR;
                const int gs = gi ^ (row & 7);
                *(u16x8*)&hstage[(row * GR + gs) * 8] =
                    *(const u16x8*)(hsrc + (size_t)(b0 + row) * U_ + gi * 8);
            }
        }
        __syncthreads();   // B2: h staged

        f32x4 acc[TILES];
        #pragma unroll
        for (int tl = 0; tl < TILES; ++tl) acc[tl] = f32x4{0.f, 0.f, 0.f, 0.f};
        if (t > 0) {
            #pragma unroll
            for (int kt = 0; kt < KT; ++kt) {
                const int gs = (kt * 4 + hi) ^ (lo & 7);
                const bf16x8 a = *(const bf16x8*)&hstage[(lo * GR + gs) * 8];
                #pragma unroll
                for (int tl = 0; tl < TILES; ++tl)
                    acc[tl] = __builtin_amdgcn_mfma_f32_16x16x32_bf16(a, bfr[tl][kt], acc[tl], 0, 0, 0);
            }
        }

        float p[TILES][4];
        #pragma unroll
        for (int tl = 0; tl < TILES; ++tl)
            #pragma unroll
            for (int r = 0; r < 4; ++r)
                p[tl][r] = acc[tl][r] + bf2f(xr[tl][r]);

        if (g4 != 2) {
            const int slot = (g4 == 3) ? 2 : g4;    // i->0, f->1, o->2
            #pragma unroll
            for (int tl = 0; tl < TILES; ++tl)
                #pragma unroll
                for (int r = 0; r < 4; ++r)
                    ex[((slot * 2 + chh) * JH + tl * 16 + lo) * 17 + hi * 4 + r] = sigmoidf_(p[tl][r]);
        }
        __syncthreads();   // B3: gates exchanged

        if (g4 == 2) {
            ushortT* hwr = hring + (size_t)(t & (RING - 1)) * S;
            #pragma unroll
            for (int tl = 0; tl < TILES; ++tl) {
                const int jh = tl * 16 + lo;
                const int j  = gc[tl] - 2 * U_;
                #pragma unroll
                for (int r = 0; r < 4; ++r) {
                    const int row = hi * 4 + r;
                    const float i_ = ex[((0 * 2 + chh) * JH + jh) * 17 + row];
                    const float f_ = ex[((1 * 2 + chh) * JH + jh) * 17 + row];
                    const float o_ = ex[((2 * 2 + chh) * JH + jh) * 17 + row];
                    creg[tl][r] = f_ * creg[tl][r] + i_ * fmaxf(p[tl][r], 0.f);
                    const float hn = o_ * fmaxf(creg[tl][r], 0.f);
                    hwr[(size_t)(b0 + row) * U_ + j] = f2bf(hn);
                }
            }
        }
        asm volatile("s_waitcnt vmcnt(0)" ::: "memory");
        __syncthreads();   // B4: all h stores drained
        if (tid == 0)
            __hip_atomic_store(&Fown[(grp * WPG + wgj) * 16], (unsigned)(t + 1),
                               __ATOMIC_RELEASE, AGT);
    }
}

// ---------------------------------------------------------------------------
// GEMM worker role: per step t produce xg[t] slab tile (64 m-cols x 128 b).
// MODE0: x = embbf gathered via tokens; MODE1: x = h-ring slab t ([128][KP]).
// Waits: upstream flags >= t+1 (producer of x), guard flags >= t-(RING-1)
// (consumers of the xg slab being overwritten). Releases X[mtile,phase]=t+1.
// ---------------------------------------------------------------------------
template<int MODE, int NGATES, int KP>
__device__ void worker_role(
    int mtile, int phase, int nph,
    const ushortT* __restrict__ WT,     // [NGATES][KP] bf16
    const float* __restrict__ bias,
    const ushortT* __restrict__ hsrcring,
    const ushortT* __restrict__ embbf,
    const int* __restrict__ tokens,
    ushortT* __restrict__ xgring,       // [RING][8][NGATES][16]
    unsigned* Fup, int nUp,
    unsigned* Fguard, int nGd,
    unsigned* Xrel,
    char* smem)
{
    ushortT* Wl   = (ushortT*)smem;              // [64][32]
    ushortT* Xl   = (ushortT*)(smem + 4096);     // [128][32]
    int*     tokL = (int*)(smem + 4096 + 8192);  // [128]

    const int tid = threadIdx.x, w = tid >> 6, lane = tid & 63;
    const int lo = lane & 15, hi = lane >> 4;
    const int mt4 = w & 3, nh = w >> 2;
    const int m0 = mtile * 64;

    for (int t = phase; t < SEQT; t += nph) {
        if (w == 0) {
            int guard = 0; bool ok;
            do {
                bool pred = (lane < nUp) ? ((int)ald(&Fup[lane * 16]) >= t + 1) : true;
                ok = __all(pred);
                if (!ok) __builtin_amdgcn_s_sleep(1);
            } while (!ok && ++guard < LIM);
            guard = 0;
            do {
                bool pred = (lane < nGd) ? ((int)ald(&Fguard[lane * 16]) >= t - (RING - 1)) : true;
                ok = __all(pred);
                if (!ok) __builtin_amdgcn_s_sleep(1);
            } while (!ok && ++guard < LIM);
            if (lane == 0)
                (void)__hip_atomic_load(&Fguard[0], __ATOMIC_ACQUIRE, AGT);
        }
        __syncthreads();

        if (MODE == 0) {
            if (tid < 128) tokL[tid] = tokens[tid * SEQT + t];
            __syncthreads();
        }
        const ushortT* hslab = (MODE == 1)
            ? hsrcring + (size_t)(t & (RING - 1)) * 128 * KP : nullptr;

        f32x4 acc[4];
        #pragma unroll
        for (int nn = 0; nn < 4; ++nn) acc[nn] = f32x4{0.f, 0.f, 0.f, 0.f};

        for (int k0 = 0; k0 < KP; k0 += 32) {
            for (int i = tid; i < 768; i += 512) {
                if (i < 256) {
                    const int row = i >> 2, gq = i & 3;
                    const int gs = gq ^ ((row >> 1) & 3);
                    *(u16x8*)&Wl[row * 32 + gs * 8] =
                        *(const u16x8*)(WT + (size_t)(m0 + row) * KP + k0 + gq * 8);
                } else {
                    const int idx = i - 256, row = idx >> 2, gq = idx & 3;
                    const int gs = gq ^ ((row >> 1) & 3);
                    const ushortT* xs = (MODE == 1)
                        ? hslab + (size_t)row * KP + k0 + gq * 8
                        : embbf + (size_t)tokL[row] * KP + k0 + gq * 8;
                    *(u16x8*)&Xl[row * 32 + gs * 8] = *(const u16x8*)xs;
                }
            }
            __syncthreads();
            {
                const int arow = mt4 * 16 + lo;
                const bf16x8 a = *(const bf16x8*)&Wl[arow * 32 + (hi ^ ((arow >> 1) & 3)) * 8];
                #pragma unroll
                for (int nn = 0; nn < 4; ++nn) {
                    const int brow = nh * 64 + nn * 16 + lo;
                    const bf16x8 b = *(const bf16x8*)&Xl[brow * 32 + (hi ^ ((brow >> 1) & 3)) * 8];
                    acc[nn] = __builtin_amdgcn_mfma_f32_16x16x32_bf16(a, b, acc[nn], 0, 0, 0);
                }
            }
            __syncthreads();
        }

        // epilogue: +bias, bf16, store to xg ring slab t
        const size_t slab = (size_t)(t & (RING - 1)) * 8;
        #pragma unroll
        for (int nn = 0; nn < 4; ++nn) {
            const int bb = nh * 64 + nn * 16 + lo;
            #pragma unroll
            for (int j = 0; j < 4; ++j) {
                const int m = m0 + mt4 * 16 + hi * 4 + j;
                xgring[((slab + (bb >> 4)) * NGATES + m) * 16 + (bb & 15)] =
                    f2bf(acc[nn][j] + bias[m]);
            }
        }
        asm volatile("s_waitcnt vmcnt(0)" ::: "memory");
        __syncthreads();
        if (tid == 0)
            __hip_atomic_store(Xrel, (unsigned)(t + 1), __ATOMIC_RELEASE, AGT);
    }
}

// ---------------------------------------------------------------------------
// Megakernel: role dispatch by blockIdx. 176 WGs x 512 thr, 1 WG/CU.
//  [0,16)   L0 rec   [16,80)  L1 rec   [80,96)  L2 rec
//  [96,128) G1 (xg1<-h0)  [128,160) G2 (xg2<-h1, 2 phases)  [160,176) G0 (xg0)
// ---------------------------------------------------------------------------
__global__ __launch_bounds__(512, 1) void mega(MegaArgs A)
{
    extern __shared__ char smem[];
    const int bid = blockIdx.x;
    if (bid < 16) {
        rec_role<NU0, 128>(bid, A.U0, A.xg0, A.h0r, A.F0, A.X0, 1, A.X1, 32, smem);
    } else if (bid < 80) {
        rec_role<NU1, 64>(bid - 16, A.U1, A.xg1, A.h1r, A.F1, A.X1, 1, A.X2, 32, smem);
    } else if (bid < 96) {
        rec_role<NU2, 128>(bid - 80, A.U2, A.xg2, A.h2r, A.F2, A.X2, 2, nullptr, 0, smem);
    } else if (bid < 128) {
        const int mt = bid - 96;
        worker_role<1, 4 * NU1, NU0>(mt, 0, 1, A.W1T, A.b1, A.h0r, nullptr, nullptr,
                                     A.xg1, A.F0, 16, A.F1, 64, A.X1 + mt * 16, smem);
    } else if (bid < 160) {
        const int rid = bid - 128;
        const int mt = rid & 15, ph = rid >> 4;
        worker_role<1, 4 * NU2, NU1>(mt, ph, 2, A.W2T, A.b2, A.h1r, nullptr, nullptr,
                                     A.xg2, A.F1, 64, A.F2, 16, A.X2 + (mt * 2 + ph) * 16, smem);
    } else {
        const int mt = bid - 160;
        worker_role<0, 4 * NU0, KP0>(mt, 0, 1, A.W0T, A.b0, nullptr, A.embbf, A.tokens,
                                     A.xg0, nullptr, 0, A.F0, 16, A.X0 + mt * 16, smem);
    }
}

// ---------------------------------------------------------------------------
// Head: out[b] = sigmoid( relu(h2[b,:] @ Wd + bd) @ Wc + bc ), h2 bf16 [128][256]
// ---------------------------------------------------------------------------
__global__ __launch_bounds__(64) void head_kernel(
    const ushortT* __restrict__ h2,
    const float* __restrict__ Wd,
    const float* __restrict__ bd,
    const float* __restrict__ Wc,
    const float* __restrict__ bc,
    float* __restrict__ out)
{
    const int b = blockIdx.x;
    const int j = threadIdx.x;
    float a = bd[j];
    const ushortT* hrow = h2 + (size_t)b * NU2;
    #pragma unroll 4
    for (int k = 0; k < NU2; ++k)
        a += bf2f(hrow[k]) * Wd[(size_t)k * NDENSE + j];
    a = fmaxf(a, 0.f) * Wc[j];
    #pragma unroll
    for (int off = 32; off > 0; off >>= 1)
        a += __shfl_down(a, off);
    if (j == 0)
        out[b] = 1.f / (1.f + expf(-(a + bc[0])));
}

// ---------------------------------------------------------------------------
extern "C" void kernel_launch(void* const* d_in, const int* in_sizes, int n_in,
                              void* d_out, int out_size, void* d_ws, size_t ws_size,
                              hipStream_t stream)
{
    const int*   tokens = (const int*)  d_in[0];
    const float* emb    = (const float*)d_in[1];
    const float* W0     = (const float*)d_in[2];
    const float* Ur0    = (const float*)d_in[3];
    const float* b0v    = (const float*)d_in[4];
    const float* W1     = (const float*)d_in[5];
    const float* Ur1    = (const float*)d_in[6];
    const float* b1v    = (const float*)d_in[7];
    const float* W2     = (const float*)d_in[8];
    const float* Ur2    = (const float*)d_in[9];
    const float* b2v    = (const float*)d_in[10];
    const float* Wd     = (const float*)d_in[11];
    const float* bd     = (const float*)d_in[12];
    const float* Wc     = (const float*)d_in[13];
    const float* bc     = (const float*)d_in[14];
    float* out = (float*)d_out;

    char* p = (char*)d_ws;
    auto alloc = [&](size_t bytes) -> char* {
        char* q = p; p += (bytes + 255) & ~(size_t)255; return q;
    };
    ushortT* xg0   = (ushortT*)alloc((size_t)RING * 8 * 1024 * 16 * 2);  // 4 MB
    ushortT* xg1   = (ushortT*)alloc((size_t)RING * 8 * 2048 * 16 * 2);  // 8 MB
    ushortT* xg2   = (ushortT*)alloc((size_t)RING * 8 * 1024 * 16 * 2);  // 4 MB
    ushortT* h0r   = (ushortT*)alloc((size_t)RING * 128 * NU0 * 2);      // 1 MB
    ushortT* h1r   = (ushortT*)alloc((size_t)RING * 128 * NU1 * 2);      // 2 MB
    ushortT* h2r   = (ushortT*)alloc((size_t)RING * 128 * NU2 * 2);      // 1 MB
    ushortT* W0T   = (ushortT*)alloc((size_t)1024 * KP0 * 2);
    ushortT* W1T   = (ushortT*)alloc((size_t)2048 * NU0 * 2);
    ushortT* W2T   = (ushortT*)alloc((size_t)1024 * NU1 * 2);
    ushortT* embbf = (ushortT*)alloc((size_t)VOCABN * KP0 * 2);
    unsigned* flg  = (unsigned*)alloc(16384);

    // flag partition (16-word stride per flag)
    unsigned* F0 = flg;            // 16 flags
    unsigned* F1 = F0 + 16 * 16;   // 64
    unsigned* F2 = F1 + 64 * 16;   // 16
    unsigned* X0 = F2 + 16 * 16;   // 16
    unsigned* X1 = X0 + 16 * 16;   // 32
    unsigned* X2 = X1 + 32 * 16;   // 32 (16 mtiles x 2 phases)

    hipMemsetAsync(flg, 0, 16384, stream);

    convert_WT<<<512, 256, 0, stream>>>(W0, W0T, EMB_D, 1024, KP0, 1024 * KP0);
    convert_WT<<<512, 256, 0, stream>>>(W1, W1T, NU0, 2048, NU0, 2048 * NU0);
    convert_WT<<<512, 256, 0, stream>>>(W2, W2T, NU1, 1024, NU1, 1024 * NU1);
    convert_emb<<<1024, 256, 0, stream>>>(emb, embbf);

    MegaArgs A;
    A.tokens = tokens; A.embbf = embbf;
    A.W0T = W0T; A.W1T = W1T; A.W2T = W2T;
    A.b0 = b0v; A.b1 = b1v; A.b2 = b2v;
    A.U0 = Ur0; A.U1 = Ur1; A.U2 = Ur2;
    A.xg0 = xg0; A.xg1 = xg1; A.xg2 = xg2;
    A.h0r = h0r; A.h1r = h1r; A.h2r = h2r;
    A.F0 = F0; A.F1 = F1; A.F2 = F2; A.X0 = X0; A.X1 = X1; A.X2 = X2;

    void* args[] = {&A};
    hipLaunchCooperativeKernel((void*)mega, dim3(176), dim3(512), args, 34816, stream);

    // final h of layer 2 = ring slab (511 & 15) = 15
    head_kernel<<<BATCH, 64, 0, stream>>>(h2r + (size_t)15 * 128 * NU2,
                                          Wd, bd, Wc, bc, out);
}